// Round 14
// baseline (434.989 us; speedup 1.0000x reference)
//
#include <hip/hip_runtime.h>
#include <hip/hip_fp16.h>
#include <math.h>

#define IN_DIM 128
#define HID 32
#define HEADS 12
#define FDIM (HEADS*HID)   // 384
#define SLOPE 0.2f

typedef __attribute__((ext_vector_type(8))) short short8;
typedef __attribute__((ext_vector_type(4))) float float4v;
typedef __attribute__((ext_vector_type(4))) float f32x4;
typedef _Float16 hv2 __attribute__((ext_vector_type(2)));

__device__ __forceinline__ float dot2acc(hv2 a, hv2 b, float c) {
#if __has_builtin(__builtin_amdgcn_fdot2)
    return __builtin_amdgcn_fdot2(a, b, c, false);
#else
    return c + (float)a.x * (float)b.x + (float)a.y * (float)b.y;
#endif
}

// ---------------- CSR build ----------------

__global__ void hist_kernel(const int* __restrict__ dst, int* __restrict__ cnt, int E) {
    int e = blockIdx.x * blockDim.x + threadIdx.x;
    if (e < E) atomicAdd(&cnt[dst[e]], 1);
}

__global__ __launch_bounds__(256) void scan_partial_kernel(const int* __restrict__ cnt,
                                                           int* __restrict__ partials, int n) {
    int i = blockIdx.x * 256 + threadIdx.x;
    int v = (i < n) ? cnt[i] : 0;
#pragma unroll
    for (int off = 1; off < 64; off <<= 1) v += __shfl_xor(v, off);
    __shared__ int sh[4];
    if ((threadIdx.x & 63) == 0) sh[threadIdx.x >> 6] = v;
    __syncthreads();
    if (threadIdx.x == 0) partials[blockIdx.x] = sh[0] + sh[1] + sh[2] + sh[3];
}

__global__ __launch_bounds__(1024) void scan_top_kernel(int* __restrict__ partials, int nb) {
    __shared__ int sh[1024];
    int t = threadIdx.x;
    int v = (t < nb) ? partials[t] : 0;
    sh[t] = v;
    __syncthreads();
    for (int off = 1; off < 1024; off <<= 1) {
        int u = (t >= off) ? sh[t - off] : 0;
        __syncthreads();
        sh[t] += u;
        __syncthreads();
    }
    if (t < nb) partials[t] = sh[t] - v;   // exclusive
}

__global__ __launch_bounds__(256) void scan_final_kernel(const int* __restrict__ cnt,
                                                         const int* __restrict__ partials,
                                                         int* __restrict__ start,
                                                         int* __restrict__ cursor, int n) {
    __shared__ int sh[256];
    int t = threadIdx.x;
    int i = blockIdx.x * 256 + t;
    int v = (i < n) ? cnt[i] : 0;
    sh[t] = v;
    __syncthreads();
    for (int off = 1; off < 256; off <<= 1) {
        int u = (t >= off) ? sh[t - off] : 0;
        __syncthreads();
        sh[t] += u;
        __syncthreads();
    }
    int ex = sh[t] - v + partials[blockIdx.x];
    if (i < n) {
        start[i] = ex;
        cursor[i] = ex;
        if (i == n - 1) start[n] = ex + v;
    }
}

__global__ void scatter_kernel(const int* __restrict__ src, const int* __restrict__ dst,
                               int* __restrict__ cursor, int* __restrict__ srcs,
                               int* __restrict__ srcsOff, int E) {
    int e = blockIdx.x * blockDim.x + threadIdx.x;
    if (e < E) {
        int d = dst[e];
        int pos = atomicAdd(&cursor[d], 1);
        int s = src[e];
        srcs[pos] = s;
        srcsOff[pos] = s * (FDIM * 2);   // byte offset into f16 feature rows
    }
}

// ---------------- bf16 split helpers ----------------

__device__ __forceinline__ unsigned int bf16_rne(float f) {
    unsigned int u = __float_as_uint(f);
    return (u + 0x7FFFu + ((u >> 16) & 1u)) >> 16;
}

// ---------------- merged prep: weights (both layers) + att f16 ----------------

__global__ void prep_all(const float* __restrict__ Wl0, const float* __restrict__ Wr0,
                         const float* __restrict__ Wl1, const float* __restrict__ Wr1,
                         const float* __restrict__ a0, const float* __restrict__ a1,
                         short* __restrict__ Bl0h, short* __restrict__ Bl0l,
                         short* __restrict__ Br0h, short* __restrict__ Br0l,
                         short* __restrict__ Bl1h, short* __restrict__ Bl1l,
                         short* __restrict__ Br1h, short* __restrict__ Br1l,
                         _Float16* __restrict__ attH) {
    int idx = blockIdx.x * 256 + threadIdx.x;
    if (idx < 49152) {
        int k = idx / 384, n = idx - k * 384;
        float w1 = Wl0[idx], w2 = Wr0[idx];
        unsigned int h1 = bf16_rne(w1);
        unsigned int l1 = bf16_rne(w1 - __uint_as_float(h1 << 16));
        unsigned int h2 = bf16_rne(w2);
        unsigned int l2 = bf16_rne(w2 - __uint_as_float(h2 << 16));
        Bl0h[n * 128 + k] = (short)h1;  Bl0l[n * 128 + k] = (short)l1;
        Br0h[n * 128 + k] = (short)h2;  Br0l[n * 128 + k] = (short)l2;
    } else if (idx < 61440) {
        int i2 = idx - 49152;
        int k = i2 / 384, n = i2 - k * 384;
        float w1 = Wl1[i2], w2 = Wr1[i2];
        unsigned int h1 = bf16_rne(w1);
        unsigned int l1 = bf16_rne(w1 - __uint_as_float(h1 << 16));
        unsigned int h2 = bf16_rne(w2);
        unsigned int l2 = bf16_rne(w2 - __uint_as_float(h2 << 16));
        Bl1h[n * 32 + k] = (short)h1;  Bl1l[n * 32 + k] = (short)l1;
        Br1h[n * 32 + k] = (short)h2;  Br1l[n * 32 + k] = (short)l2;
    } else if (idx < 62208) {
        int i2 = idx - 61440;
        attH[i2] = (_Float16)((i2 < 384) ? a0[i2] : a1[i2 - 384]);
    }
}

// ---------------- input prep: x fp32 -> bf16 hi/lo planes (float4 vectorized) ----------------

__global__ void conv_x_kernel(const float* __restrict__ A, short* __restrict__ Ah,
                              short* __restrict__ Al, int total4) {
    int i = blockIdx.x * 256 + threadIdx.x;
    if (i >= total4) return;
    float4 v = ((const float4*)A)[i];
    float fs[4] = {v.x, v.y, v.z, v.w};
    unsigned int hb[4], lb[4];
#pragma unroll
    for (int t = 0; t < 4; t++) {
        hb[t] = bf16_rne(fs[t]);
        lb[t] = bf16_rne(fs[t] - __uint_as_float(hb[t] << 16));
    }
    uint2 hp, lp;
    hp.x = hb[0] | (hb[1] << 16); hp.y = hb[2] | (hb[3] << 16);
    lp.x = lb[0] | (lb[1] << 16); lp.y = lb[2] | (lb[3] << 16);
    ((uint2*)Ah)[i] = hp;
    ((uint2*)Al)[i] = lp;
}

// ---------------- bf16x3 MFMA GEMM pair, pre-split A, LDS-staged w/ register prefetch ----------------
// C{1,2}[M x 384] = A @ B{1,2} + bias via Ahi.Bhi + Ahi.Blo + Alo.Bhi.
// r12 LDS structure (proven) + tile t+1 global loads issued into regs right after
// the first barrier, overlapping tile t's ds_read+MFMA. Single LDS buffer (4 blk/CU).
// grid.y = 6 (3 col-tiles x 2 matrices). K multiple of 32. f16 C via LDS-transpose epilogue.

__global__ __launch_bounds__(256) void gemm_pair_mfma_db(
    const short* __restrict__ Ahi, const short* __restrict__ Alo,
    const short* __restrict__ B1h, const short* __restrict__ B1l,
    const float* __restrict__ bias1, __half* __restrict__ C1,
    const short* __restrict__ B2h, const short* __restrict__ B2l,
    const float* __restrict__ bias2, __half* __restrict__ C2,
    int M, int K) {
    __shared__ __align__(16) unsigned char smem[33792];
    uint4* AsHi = (uint4*)smem;
    uint4* AsLo = AsHi + 512;
    uint4* BsHi = AsLo + 512;
    uint4* BsLo = BsHi + 512;
    int tid = threadIdx.x;
    int lane = tid & 63;
    int wave = tid >> 6;
    int wm = wave & 1, wn = wave >> 1;
    int rowBase = blockIdx.x * 128;
    bool second = blockIdx.y >= 3;
    int colBase = (blockIdx.y - (second ? 3 : 0)) * 128;
    const short* Bh  = second ? B2h : B1h;
    const short* Bl  = second ? B2l : B1l;
    const float* bias = second ? bias2 : bias1;
    __half*      C    = second ? C2 : C1;

    // chunk geometry (compile-time per i)
    // A: c = i*256+tid, o=c>>7, r=c&127, slot=(r>>4)*64+(o<<4)+(r&15)
    // B: c = i*256+tid, h=i>>1, o=(c>>7)&3, n=c&127, same slot formula on n
    int cA0 = tid,        oA0 = cA0 >> 7, rA0 = cA0 & 127;
    int cA1 = 256 + tid,  oA1 = cA1 >> 7, rA1 = cA1 & 127;
    int sA0 = (rA0 >> 4) * 64 + (oA0 << 4) + (rA0 & 15);
    int sA1 = (rA1 >> 4) * 64 + (oA1 << 4) + (rA1 & 15);
    bool vA0 = rowBase + rA0 < M, vA1 = rowBase + rA1 < M;
    long aOff0 = (long)(rowBase + rA0) * K + oA0 * 8;
    long aOff1 = (long)(rowBase + rA1) * K + oA1 * 8;
    int sB[4]; long bOff[4];
#pragma unroll
    for (int i = 0; i < 4; i++) {
        int c = i * 256 + tid;
        int o = (c >> 7) & 3, n = c & 127;
        sB[i] = (n >> 4) * 64 + (o << 4) + (n & 15);
        bOff[i] = (long)(colBase + n) * K + o * 8;
    }

    float4v acc[4][4];
#pragma unroll
    for (int i = 0; i < 4; i++)
#pragma unroll
        for (int j = 0; j < 4; j++) acc[i][j] = (float4v){0.f, 0.f, 0.f, 0.f};

    uint4 z4 = make_uint4(0, 0, 0, 0);
    uint4 pA0h, pA0l, pA1h, pA1l, pB[4];
    // preload tile 0
    pA0h = vA0 ? *(const uint4*)(Ahi + aOff0) : z4;
    pA0l = vA0 ? *(const uint4*)(Alo + aOff0) : z4;
    pA1h = vA1 ? *(const uint4*)(Ahi + aOff1) : z4;
    pA1l = vA1 ? *(const uint4*)(Alo + aOff1) : z4;
    pB[0] = *(const uint4*)(Bh + bOff[0]);
    pB[1] = *(const uint4*)(Bh + bOff[1]);
    pB[2] = *(const uint4*)(Bl + bOff[2]);
    pB[3] = *(const uint4*)(Bl + bOff[3]);

    for (int kt = 0; kt < K; kt += 32) {
        // commit staged regs to LDS
        AsHi[sA0] = pA0h; AsLo[sA0] = pA0l;
        AsHi[sA1] = pA1h; AsLo[sA1] = pA1l;
        BsHi[sB[0]] = pB[0]; BsHi[sB[1]] = pB[1];
        BsLo[sB[2]] = pB[2]; BsLo[sB[3]] = pB[3];
        __syncthreads();

        // prefetch next tile (overlaps ds_read+MFMA below)
        int kn = kt + 32;
        if (kn < K) {
            pA0h = vA0 ? *(const uint4*)(Ahi + aOff0 + kn) : z4;
            pA0l = vA0 ? *(const uint4*)(Alo + aOff0 + kn) : z4;
            pA1h = vA1 ? *(const uint4*)(Ahi + aOff1 + kn) : z4;
            pA1l = vA1 ? *(const uint4*)(Alo + aOff1 + kn) : z4;
            pB[0] = *(const uint4*)(Bh + bOff[0] + kn);
            pB[1] = *(const uint4*)(Bh + bOff[1] + kn);
            pB[2] = *(const uint4*)(Bl + bOff[2] + kn);
            pB[3] = *(const uint4*)(Bl + bOff[3] + kn);
        }

        short8 ah[4], al[4], bh[4], blv[4];
#pragma unroll
        for (int i = 0; i < 4; i++) {
            ah[i]  = ((const short8*)AsHi)[(wm * 4 + i) * 64 + lane];
            al[i]  = ((const short8*)AsLo)[(wm * 4 + i) * 64 + lane];
            bh[i]  = ((const short8*)BsHi)[(wn * 4 + i) * 64 + lane];
            blv[i] = ((const short8*)BsLo)[(wn * 4 + i) * 64 + lane];
        }
#pragma unroll
        for (int i = 0; i < 4; i++)
#pragma unroll
            for (int j = 0; j < 4; j++) {
                acc[i][j] = __builtin_amdgcn_mfma_f32_16x16x32_bf16(ah[i], bh[j],  acc[i][j], 0, 0, 0);
                acc[i][j] = __builtin_amdgcn_mfma_f32_16x16x32_bf16(ah[i], blv[j], acc[i][j], 0, 0, 0);
                acc[i][j] = __builtin_amdgcn_mfma_f32_16x16x32_bf16(al[i], bh[j],  acc[i][j], 0, 0, 0);
            }
        __syncthreads();
    }

    // coalesced epilogue via LDS transpose (C/D layout: col=lane&15, row=(lane>>4)*4+reg)
    float* Ct = (float*)smem;
    int cq = lane >> 4, cn = lane & 15;
#pragma unroll
    for (int ph = 0; ph < 2; ph++) {
        if (wm == ph) {
#pragma unroll
            for (int i = 0; i < 4; i++)
#pragma unroll
                for (int j = 0; j < 4; j++) {
                    int lr = i * 16 + cq * 4;
                    int lc = wn * 64 + j * 16 + cn;
#pragma unroll
                    for (int r = 0; r < 4; r++)
                        Ct[(lr + r) * 132 + lc] = acc[i][j][r];
                }
        }
        __syncthreads();
#pragma unroll
        for (int k = 0; k < 4; k++) {
            int o = k * 256 + tid;
            int lr = o >> 4;
            int oc = (o & 15) << 3;
            int gr = rowBase + ph * 64 + lr;
            if (gr < M) {
                float4 f0 = *(float4*)&Ct[lr * 132 + oc];
                float4 f1 = *(float4*)&Ct[lr * 132 + oc + 4];
                int gc = colBase + oc;
                float4 b0 = *(const float4*)(bias + gc);
                float4 b1 = *(const float4*)(bias + gc + 4);
                __half2 p0 = __floats2half2_rn(f0.x + b0.x, f0.y + b0.y);
                __half2 p1 = __floats2half2_rn(f0.z + b0.z, f0.w + b0.w);
                __half2 p2 = __floats2half2_rn(f1.x + b1.x, f1.y + b1.y);
                __half2 p3 = __floats2half2_rn(f1.z + b1.z, f1.w + b1.w);
                uint4 ov;
                ov.x = *(unsigned int*)&p0;
                ov.y = *(unsigned int*)&p1;
                ov.z = *(unsigned int*)&p2;
                ov.w = *(unsigned int*)&p3;
                *(uint4*)(C + (size_t)gr * FDIM + gc) = ov;
            }
        }
        __syncthreads();
    }
}

// ---------------- per-node GATv2 aggregation (one WAVE-sized block per node) ----------------

__global__ __launch_bounds__(64) void agg_kernel(const __half* __restrict__ xl,
                                                 const __half* __restrict__ xr,
                                                 const _Float16* __restrict__ att_h,
                                                 const float* __restrict__ bias,
                                                 const int* __restrict__ start,
                                                 const int* __restrict__ srcsOff,
                                                 short* __restrict__ houtHi,
                                                 short* __restrict__ houtLo,
                                                 const float* __restrict__ Wl,
                                                 const float* __restrict__ bl,
                                                 const float* __restrict__ Wr,
                                                 const float* __restrict__ br,
                                                 float* __restrict__ xloB,
                                                 float* __restrict__ xroB, int N) {
    int node = blockIdx.x;
    if (node >= N) return;
    int lane = threadIdx.x & 63;
    int hl = lane & 31;
    int half_ = lane >> 5;
    int cb = hl << 3;

    long nodeOff = (long)node * (FDIM * 2);
    hv2 xr2[6], at2[6];
    f32x4 acc[3];
    float s[3];
#pragma unroll
    for (int c = 0; c < 3; c++) {
        uint2 ur = *(const uint2*)((const char*)xr + nodeOff + c * 256 + cb);
        xr2[2*c]   = __builtin_bit_cast(hv2, ur.x);
        xr2[2*c+1] = __builtin_bit_cast(hv2, ur.y);
        uint2 ua = *(const uint2*)((const char*)att_h + c * 256 + cb);
        at2[2*c]   = __builtin_bit_cast(hv2, ua.x);
        at2[2*c+1] = __builtin_bit_cast(hv2, ua.y);
        acc[c] = (f32x4){0.f, 0.f, 0.f, 0.f};
        s[c] = 0.f;
    }
    const hv2 sl2 = {(_Float16)SLOPE, (_Float16)SLOPE};
    const char* xlb = (const char*)xl;

    int e0 = start[node], e1 = start[node + 1];

    for (int b = e0 - 1; b < e1; b += 4) {
        hv2 xa[2][6];
        float mask[2];
#pragma unroll
        for (int p = 0; p < 2; p++) {
            int myIdx = b + p * 2 + half_;
            int ic = min(myIdx, e1 - 1);
            long off = (ic < e0) ? nodeOff : (long)srcsOff[ic];
            mask[p] = (myIdx < e1) ? 0.f : -1e30f;
            const char* base = xlb + off + cb;
            uint2 u0 = *(const uint2*)(base);
            uint2 u1 = *(const uint2*)(base + 256);
            uint2 u2 = *(const uint2*)(base + 512);
            xa[p][0] = __builtin_bit_cast(hv2, u0.x); xa[p][1] = __builtin_bit_cast(hv2, u0.y);
            xa[p][2] = __builtin_bit_cast(hv2, u1.x); xa[p][3] = __builtin_bit_cast(hv2, u1.y);
            xa[p][4] = __builtin_bit_cast(hv2, u2.x); xa[p][5] = __builtin_bit_cast(hv2, u2.y);
        }
#pragma unroll
        for (int p = 0; p < 2; p++) {
            float pc[3];
#pragma unroll
            for (int c = 0; c < 3; c++) {
                hv2 t0 = xa[p][2*c]   + xr2[2*c];
                hv2 t1 = xa[p][2*c+1] + xr2[2*c+1];
                t0 = __builtin_elementwise_max(t0, t0 * sl2);
                t1 = __builtin_elementwise_max(t1, t1 * sl2);
                pc[c] = dot2acc(t1, at2[2*c+1], dot2acc(t0, at2[2*c], 0.f));
            }
#pragma unroll
            for (int st = 1; st <= 4; st <<= 1) {
                pc[0] += __shfl_xor(pc[0], st);
                pc[1] += __shfl_xor(pc[1], st);
                pc[2] += __shfl_xor(pc[2], st);
            }
#pragma unroll
            for (int c = 0; c < 3; c++) {
                float a = __expf(pc[c] + mask[p]);
                s[c] += a;
                acc[c].x = fmaf(a, (float)xa[p][2*c].x,   acc[c].x);
                acc[c].y = fmaf(a, (float)xa[p][2*c].y,   acc[c].y);
                acc[c].z = fmaf(a, (float)xa[p][2*c+1].x, acc[c].z);
                acc[c].w = fmaf(a, (float)xa[p][2*c+1].y, acc[c].w);
            }
        }
    }

    // merge halves
#pragma unroll
    for (int c = 0; c < 3; c++) {
        acc[c].x += __shfl_xor(acc[c].x, 32);
        acc[c].y += __shfl_xor(acc[c].y, 32);
        acc[c].z += __shfl_xor(acc[c].z, 32);
        acc[c].w += __shfl_xor(acc[c].w, 32);
        s[c] += __shfl_xor(s[c], 32);
    }
    f32x4 v[3];
#pragma unroll
    for (int c = 0; c < 3; c++) {
        float inv = 1.f / (s[c] + 1e-16f);
        f32x4 iv = {inv, inv, inv, inv};
        v[c] = acc[c] * iv;
    }
#pragma unroll
    for (int st = 8; st <= 16; st <<= 1) {
#pragma unroll
        for (int c = 0; c < 3; c++) {
            v[c].x += __shfl_xor(v[c].x, st);
            v[c].y += __shfl_xor(v[c].y, st);
            v[c].z += __shfl_xor(v[c].z, st);
            v[c].w += __shfl_xor(v[c].w, st);
        }
    }
    if (lane < 8) {
        f32x4 b4 = *(const f32x4*)(bias + (hl << 2));
        f32x4 o = (v[0] + v[1] + v[2]) * (f32x4){1.f/12.f, 1.f/12.f, 1.f/12.f, 1.f/12.f} + b4;
        o.x = o.x > 0.f ? o.x : expm1f(o.x);
        o.y = o.y > 0.f ? o.y : expm1f(o.y);
        o.z = o.z > 0.f ? o.z : expm1f(o.z);
        o.w = o.w > 0.f ? o.w : expm1f(o.w);
        if (houtHi) {
            float fs[4] = {o.x, o.y, o.z, o.w};
            unsigned int hb[4], lb[4];
#pragma unroll
            for (int t = 0; t < 4; t++) {
                hb[t] = bf16_rne(fs[t]);
                lb[t] = bf16_rne(fs[t] - __uint_as_float(hb[t] << 16));
            }
            uint2 hp, lp;
            hp.x = hb[0] | (hb[1] << 16); hp.y = hb[2] | (hb[3] << 16);
            lp.x = lb[0] | (lb[1] << 16); lp.y = lb[2] | (lb[3] << 16);
            *(uint2*)(houtHi + (size_t)node * 32 + (hl << 2)) = hp;
            *(uint2*)(houtLo + (size_t)node * 32 + (hl << 2)) = lp;
        }
        if (Wl) {
            f32x4 wl0 = *(const f32x4*)(Wl + (hl << 3));
            f32x4 wl1 = *(const f32x4*)(Wl + (hl << 3) + 4);
            f32x4 wr0 = *(const f32x4*)(Wr + (hl << 3));
            f32x4 wr1 = *(const f32x4*)(Wr + (hl << 3) + 4);
            float l0 = o.x * wl0.x + o.y * wl0.z + o.z * wl1.x + o.w * wl1.z;
            float l1 = o.x * wl0.y + o.y * wl0.w + o.z * wl1.y + o.w * wl1.w;
            float r0 = o.x * wr0.x + o.y * wr0.z + o.z * wr1.x + o.w * wr1.z;
            float r1 = o.x * wr0.y + o.y * wr0.w + o.z * wr1.y + o.w * wr1.w;
#pragma unroll
            for (int st = 1; st <= 4; st <<= 1) {
                l0 += __shfl_xor(l0, st); l1 += __shfl_xor(l1, st);
                r0 += __shfl_xor(r0, st); r1 += __shfl_xor(r1, st);
            }
            if (hl == 0) {
                xloB[2 * node]     = l0 + bl[0];
                xloB[2 * node + 1] = l1 + bl[1];
                xroB[2 * node]     = r0 + br[0];
                xroB[2 * node + 1] = r1 + br[1];
            }
        }
    }
}

// ---------------- output aggregation (heads=1, C=2) ----------------

__global__ void out_agg_kernel(const float* __restrict__ xlo, const float* __restrict__ xro,
                               const float* __restrict__ atto, const float* __restrict__ biaso,
                               const int* __restrict__ start, const int* __restrict__ srcs,
                               float* __restrict__ out, int N) {
    int i = blockIdx.x * blockDim.x + threadIdx.x;
    if (i >= N) return;
    float a0 = atto[0], a1 = atto[1];
    float xr0 = xro[2 * i], xr1 = xro[2 * i + 1];
    float s = 0.f, acc0 = 0.f, acc1 = 0.f;
    int e0 = start[i], e1 = start[i + 1];
    for (int idx = e0 - 1; idx < e1; ++idx) {
        int j = (idx < e0) ? i : srcs[idx];
        float x0 = xlo[2 * j], x1 = xlo[2 * j + 1];
        float t0 = x0 + xr0, t1 = x1 + xr1;
        t0 = fmaxf(t0, SLOPE * t0);
        t1 = fmaxf(t1, SLOPE * t1);
        float L = a0 * t0 + a1 * t1;
        float a = __expf(L);
        s += a;
        acc0 = fmaf(a, x0, acc0);
        acc1 = fmaf(a, x1, acc1);
    }
    float inv = 1.0f / (s + 1e-16f);
    out[2 * i]     = acc0 * inv + biaso[0];
    out[2 * i + 1] = acc1 * inv + biaso[1];
}

// ---------------- launch ----------------

extern "C" void kernel_launch(void* const* d_in, const int* in_sizes, int n_in,
                              void* d_out, int out_size, void* d_ws, size_t ws_size,
                              hipStream_t stream) {
    const float* x    = (const float*)d_in[0];
    const int*   ei   = (const int*)d_in[1];
    const float* Wl0  = (const float*)d_in[2];
    const float* bl0  = (const float*)d_in[3];
    const float* Wr0  = (const float*)d_in[4];
    const float* br0  = (const float*)d_in[5];
    const float* att0 = (const float*)d_in[6];
    const float* bias0= (const float*)d_in[7];
    const float* Wl1  = (const float*)d_in[8];
    const float* bl1  = (const float*)d_in[9];
    const float* Wr1  = (const float*)d_in[10];
    const float* br1  = (const float*)d_in[11];
    const float* att1 = (const float*)d_in[12];
    const float* bias1= (const float*)d_in[13];
    const float* Wlo  = (const float*)d_in[14];
    const float* blo  = (const float*)d_in[15];
    const float* Wro  = (const float*)d_in[16];
    const float* bro  = (const float*)d_in[17];
    const float* atto = (const float*)d_in[18];
    const float* biaso= (const float*)d_in[19];

    const int N = in_sizes[0] / IN_DIM;
    const int E = in_sizes[1] / 2;

    char* ws = (char*)d_ws;
    size_t off = 0;
    auto take = [&](size_t bytes) -> char* {
        char* p = ws + off;
        off += (bytes + 255) & ~(size_t)255;
        return p;
    };
    __half* xlf = (__half*)take((size_t)N * FDIM * 2);
    __half* xrf = (__half*)take((size_t)N * FDIM * 2);
    float* xloB = (float*)take((size_t)N * 2 * 4);
    float* xroB = (float*)take((size_t)N * 2 * 4);
    int* cnt    = (int*)take((size_t)N * 4);
    int* startA = (int*)take((size_t)(N + 1) * 4);
    int* cursor = (int*)take((size_t)N * 4);
    int* srcs   = (int*)take((size_t)E * 4);
    int* srcsOff= (int*)take((size_t)E * 4);
    int  nb     = (N + 255) / 256;
    int* partials = (int*)take((size_t)nb * 4);
    short* Bl0h = (short*)take((size_t)FDIM * IN_DIM * 2);
    short* Bl0l = (short*)take((size_t)FDIM * IN_DIM * 2);
    short* Br0h = (short*)take((size_t)FDIM * IN_DIM * 2);
    short* Br0l = (short*)take((size_t)FDIM * IN_DIM * 2);
    short* Bl1h = (short*)take((size_t)FDIM * HID * 2);
    short* Bl1l = (short*)take((size_t)FDIM * HID * 2);
    short* Br1h = (short*)take((size_t)FDIM * HID * 2);
    short* Br1l = (short*)take((size_t)FDIM * HID * 2);
    short* xh   = (short*)take((size_t)N * IN_DIM * 2);
    short* xlo_ = (short*)take((size_t)N * IN_DIM * 2);
    short* h0h  = (short*)take((size_t)N * HID * 2);
    short* h0l  = (short*)take((size_t)N * HID * 2);
    _Float16* attH = (_Float16*)take((size_t)768 * 2);

    const int* esrc = ei;
    const int* edst = ei + E;

    // merged prep (weights + att) + input bf16 split
    prep_all<<<(62208 + 255) / 256, 256, 0, stream>>>(Wl0, Wr0, Wl1, Wr1, att0, att1,
                                                      Bl0h, Bl0l, Br0h, Br0l,
                                                      Bl1h, Bl1l, Br1h, Br1l, attH);
    conv_x_kernel<<<((N * IN_DIM / 4) + 255) / 256, 256, 0, stream>>>(x, xh, xlo_, N * IN_DIM / 4);

    // CSR build (by destination)
    hipMemsetAsync(cnt, 0, (size_t)N * 4, stream);
    hist_kernel<<<(E + 255) / 256, 256, 0, stream>>>(edst, cnt, E);
    scan_partial_kernel<<<nb, 256, 0, stream>>>(cnt, partials, N);
    scan_top_kernel<<<1, 1024, 0, stream>>>(partials, nb);
    scan_final_kernel<<<nb, 256, 0, stream>>>(cnt, partials, startA, cursor, N);
    scatter_kernel<<<(E + 255) / 256, 256, 0, stream>>>(esrc, edst, cursor, srcs, srcsOff, E);

    dim3 ggrid((N + 127) / 128, 6);
    // layer 0
    gemm_pair_mfma_db<<<ggrid, 256, 0, stream>>>(xh, xlo_, Bl0h, Bl0l, bl0, xlf, Br0h, Br0l, br0, xrf, N, IN_DIM);
    agg_kernel<<<N, 64, 0, stream>>>(xlf, xrf, attH, bias0, startA, srcsOff,
                                     h0h, h0l, nullptr, nullptr, nullptr, nullptr,
                                     nullptr, nullptr, N);
    // layer 1
    gemm_pair_mfma_db<<<ggrid, 256, 0, stream>>>(h0h, h0l, Bl1h, Bl1l, bl1, xlf, Br1h, Br1l, br1, xrf, N, HID);
    agg_kernel<<<N, 64, 0, stream>>>(xlf, xrf, attH + 384, bias1, startA, srcsOff,
                                     nullptr, nullptr, Wlo, blo, Wro, bro,
                                     xloB, xroB, N);
    // output aggregation
    out_agg_kernel<<<(N + 255) / 256, 256, 0, stream>>>(xloB, xroB, atto, biaso, startA, srcs, (float*)d_out, N);
}

// Round 15
// 386.655 us; speedup vs baseline: 1.1250x; 1.1250x over previous
//
#include <hip/hip_runtime.h>
#include <hip/hip_fp16.h>
#include <math.h>

#define IN_DIM 128
#define HID 32
#define HEADS 12
#define FDIM (HEADS*HID)   // 384
#define SLOPE 0.2f

typedef __attribute__((ext_vector_type(8))) short short8;
typedef __attribute__((ext_vector_type(4))) float float4v;
typedef __attribute__((ext_vector_type(4))) float f32x4;
typedef _Float16 hv2 __attribute__((ext_vector_type(2)));

__device__ __forceinline__ float dot2acc(hv2 a, hv2 b, float c) {
#if __has_builtin(__builtin_amdgcn_fdot2)
    return __builtin_amdgcn_fdot2(a, b, c, false);
#else
    return c + (float)a.x * (float)b.x + (float)a.y * (float)b.y;
#endif
}

// ---------------- CSR build ----------------

__global__ void hist_kernel(const int* __restrict__ dst, int* __restrict__ cnt, int E) {
    int e = blockIdx.x * blockDim.x + threadIdx.x;
    if (e < E) atomicAdd(&cnt[dst[e]], 1);
}

__global__ __launch_bounds__(256) void scan_partial_kernel(const int* __restrict__ cnt,
                                                           int* __restrict__ partials, int n) {
    int i = blockIdx.x * 256 + threadIdx.x;
    int v = (i < n) ? cnt[i] : 0;
#pragma unroll
    for (int off = 1; off < 64; off <<= 1) v += __shfl_xor(v, off);
    __shared__ int sh[4];
    if ((threadIdx.x & 63) == 0) sh[threadIdx.x >> 6] = v;
    __syncthreads();
    if (threadIdx.x == 0) partials[blockIdx.x] = sh[0] + sh[1] + sh[2] + sh[3];
}

__global__ __launch_bounds__(1024) void scan_top_kernel(int* __restrict__ partials, int nb) {
    __shared__ int sh[1024];
    int t = threadIdx.x;
    int v = (t < nb) ? partials[t] : 0;
    sh[t] = v;
    __syncthreads();
    for (int off = 1; off < 1024; off <<= 1) {
        int u = (t >= off) ? sh[t - off] : 0;
        __syncthreads();
        sh[t] += u;
        __syncthreads();
    }
    if (t < nb) partials[t] = sh[t] - v;   // exclusive
}

__global__ __launch_bounds__(256) void scan_final_kernel(const int* __restrict__ cnt,
                                                         const int* __restrict__ partials,
                                                         int* __restrict__ start,
                                                         int* __restrict__ cursor, int n) {
    __shared__ int sh[256];
    int t = threadIdx.x;
    int i = blockIdx.x * 256 + t;
    int v = (i < n) ? cnt[i] : 0;
    sh[t] = v;
    __syncthreads();
    for (int off = 1; off < 256; off <<= 1) {
        int u = (t >= off) ? sh[t - off] : 0;
        __syncthreads();
        sh[t] += u;
        __syncthreads();
    }
    int ex = sh[t] - v + partials[blockIdx.x];
    if (i < n) {
        start[i] = ex;
        cursor[i] = ex;
        if (i == n - 1) start[n] = ex + v;
    }
}

__global__ void scatter_kernel(const int* __restrict__ src, const int* __restrict__ dst,
                               int* __restrict__ cursor, int* __restrict__ srcs,
                               int* __restrict__ srcsOff, int E) {
    int e = blockIdx.x * blockDim.x + threadIdx.x;
    if (e < E) {
        int d = dst[e];
        int pos = atomicAdd(&cursor[d], 1);
        int s = src[e];
        srcs[pos] = s;
        srcsOff[pos] = s * (FDIM * 2);   // byte offset into f16 feature rows
    }
}

// ---------------- bf16 split helpers ----------------

__device__ __forceinline__ unsigned int bf16_rne(float f) {
    unsigned int u = __float_as_uint(f);
    return (u + 0x7FFFu + ((u >> 16) & 1u)) >> 16;
}

// ---------------- merged prep: weights (both layers) + att f16 ----------------

__global__ void prep_all(const float* __restrict__ Wl0, const float* __restrict__ Wr0,
                         const float* __restrict__ Wl1, const float* __restrict__ Wr1,
                         const float* __restrict__ a0, const float* __restrict__ a1,
                         short* __restrict__ Bl0h, short* __restrict__ Bl0l,
                         short* __restrict__ Br0h, short* __restrict__ Br0l,
                         short* __restrict__ Bl1h, short* __restrict__ Bl1l,
                         short* __restrict__ Br1h, short* __restrict__ Br1l,
                         _Float16* __restrict__ attH) {
    int idx = blockIdx.x * 256 + threadIdx.x;
    if (idx < 49152) {
        int k = idx / 384, n = idx - k * 384;
        float w1 = Wl0[idx], w2 = Wr0[idx];
        unsigned int h1 = bf16_rne(w1);
        unsigned int l1 = bf16_rne(w1 - __uint_as_float(h1 << 16));
        unsigned int h2 = bf16_rne(w2);
        unsigned int l2 = bf16_rne(w2 - __uint_as_float(h2 << 16));
        Bl0h[n * 128 + k] = (short)h1;  Bl0l[n * 128 + k] = (short)l1;
        Br0h[n * 128 + k] = (short)h2;  Br0l[n * 128 + k] = (short)l2;
    } else if (idx < 61440) {
        int i2 = idx - 49152;
        int k = i2 / 384, n = i2 - k * 384;
        float w1 = Wl1[i2], w2 = Wr1[i2];
        unsigned int h1 = bf16_rne(w1);
        unsigned int l1 = bf16_rne(w1 - __uint_as_float(h1 << 16));
        unsigned int h2 = bf16_rne(w2);
        unsigned int l2 = bf16_rne(w2 - __uint_as_float(h2 << 16));
        Bl1h[n * 32 + k] = (short)h1;  Bl1l[n * 32 + k] = (short)l1;
        Br1h[n * 32 + k] = (short)h2;  Br1l[n * 32 + k] = (short)l2;
    } else if (idx < 62208) {
        int i2 = idx - 61440;
        attH[i2] = (_Float16)((i2 < 384) ? a0[i2] : a1[i2 - 384]);
    }
}

// ---------------- bf16x3 MFMA GEMM pair, fp32 A (in-kernel split), f16 C ----------------
// r12-proven structure: LDS-staged, 2 barriers/k-tile, no prefetch (spills), 4 blk/CU.

__global__ __launch_bounds__(256) void gemm_pair_mfma_f32A(
    const float* __restrict__ A,
    const short* __restrict__ B1h, const short* __restrict__ B1l,
    const float* __restrict__ bias1, __half* __restrict__ C1,
    const short* __restrict__ B2h, const short* __restrict__ B2l,
    const float* __restrict__ bias2, __half* __restrict__ C2,
    int M, int K) {
    __shared__ __align__(16) unsigned char smem[33792];
    uint4* AsHi = (uint4*)smem;
    uint4* AsLo = AsHi + 512;
    uint4* BsHi = AsLo + 512;
    uint4* BsLo = BsHi + 512;
    int tid = threadIdx.x;
    int lane = tid & 63;
    int wave = tid >> 6;
    int wm = wave & 1, wn = wave >> 1;
    int rowBase = blockIdx.x * 128;
    bool second = blockIdx.y >= 3;
    int colBase = (blockIdx.y - (second ? 3 : 0)) * 128;
    const short* Bh  = second ? B2h : B1h;
    const short* Bl  = second ? B2l : B1l;
    const float* bias = second ? bias2 : bias1;
    __half*      C    = second ? C2 : C1;

    float4v acc[4][4];
#pragma unroll
    for (int i = 0; i < 4; i++)
#pragma unroll
        for (int j = 0; j < 4; j++) acc[i][j] = (float4v){0.f, 0.f, 0.f, 0.f};

    for (int kt = 0; kt < K; kt += 32) {
#pragma unroll
        for (int i = 0; i < 2; i++) {
            int c = i * 256 + tid;
            int o = c >> 7, r = c & 127;
            int gr = rowBase + r;
            float4 f0 = make_float4(0.f, 0.f, 0.f, 0.f), f1 = f0;
            if (gr < M) {
                const float* p = A + (size_t)gr * K + kt + o * 8;
                f0 = *(const float4*)p;
                f1 = *(const float4*)(p + 4);
            }
            float fs[8] = {f0.x, f0.y, f0.z, f0.w, f1.x, f1.y, f1.z, f1.w};
            unsigned int hb[8], lb[8];
#pragma unroll
            for (int t = 0; t < 8; t++) {
                hb[t] = bf16_rne(fs[t]);
                lb[t] = bf16_rne(fs[t] - __uint_as_float(hb[t] << 16));
            }
            uint4 hi, lo;
            hi.x = hb[0] | (hb[1] << 16); hi.y = hb[2] | (hb[3] << 16);
            hi.z = hb[4] | (hb[5] << 16); hi.w = hb[6] | (hb[7] << 16);
            lo.x = lb[0] | (lb[1] << 16); lo.y = lb[2] | (lb[3] << 16);
            lo.z = lb[4] | (lb[5] << 16); lo.w = lb[6] | (lb[7] << 16);
            int slot = (r >> 4) * 64 + (o << 4) + (r & 15);
            AsHi[slot] = hi;
            AsLo[slot] = lo;
        }
#pragma unroll
        for (int i = 0; i < 4; i++) {
            int c = i * 256 + tid;
            int h = c >> 9, o = (c >> 7) & 3, n = c & 127;
            const short* src = h ? Bl : Bh;
            uint4 v = *(const uint4*)(src + (size_t)(colBase + n) * K + kt + o * 8);
            int slot = (n >> 4) * 64 + (o << 4) + (n & 15);
            if (h) BsLo[slot] = v; else BsHi[slot] = v;
        }
        __syncthreads();

        short8 ah[4], al[4], bh[4], blv[4];
#pragma unroll
        for (int i = 0; i < 4; i++) {
            ah[i]  = ((const short8*)AsHi)[(wm * 4 + i) * 64 + lane];
            al[i]  = ((const short8*)AsLo)[(wm * 4 + i) * 64 + lane];
            bh[i]  = ((const short8*)BsHi)[(wn * 4 + i) * 64 + lane];
            blv[i] = ((const short8*)BsLo)[(wn * 4 + i) * 64 + lane];
        }
#pragma unroll
        for (int i = 0; i < 4; i++)
#pragma unroll
            for (int j = 0; j < 4; j++) {
                acc[i][j] = __builtin_amdgcn_mfma_f32_16x16x32_bf16(ah[i], bh[j],  acc[i][j], 0, 0, 0);
                acc[i][j] = __builtin_amdgcn_mfma_f32_16x16x32_bf16(ah[i], blv[j], acc[i][j], 0, 0, 0);
                acc[i][j] = __builtin_amdgcn_mfma_f32_16x16x32_bf16(al[i], bh[j],  acc[i][j], 0, 0, 0);
            }
        __syncthreads();
    }

    // coalesced epilogue via LDS transpose
    float* Ct = (float*)smem;
    int cq = lane >> 4, cn = lane & 15;
#pragma unroll
    for (int ph = 0; ph < 2; ph++) {
        if (wm == ph) {
#pragma unroll
            for (int i = 0; i < 4; i++)
#pragma unroll
                for (int j = 0; j < 4; j++) {
                    int lr = i * 16 + cq * 4;
                    int lc = wn * 64 + j * 16 + cn;
#pragma unroll
                    for (int r = 0; r < 4; r++)
                        Ct[(lr + r) * 132 + lc] = acc[i][j][r];
                }
        }
        __syncthreads();
#pragma unroll
        for (int k = 0; k < 4; k++) {
            int o = k * 256 + tid;
            int lr = o >> 4;
            int oc = (o & 15) << 3;
            int gr = rowBase + ph * 64 + lr;
            if (gr < M) {
                float4 f0 = *(float4*)&Ct[lr * 132 + oc];
                float4 f1 = *(float4*)&Ct[lr * 132 + oc + 4];
                int gc = colBase + oc;
                float4 b0 = *(const float4*)(bias + gc);
                float4 b1 = *(const float4*)(bias + gc + 4);
                __half2 p0 = __floats2half2_rn(f0.x + b0.x, f0.y + b0.y);
                __half2 p1 = __floats2half2_rn(f0.z + b0.z, f0.w + b0.w);
                __half2 p2 = __floats2half2_rn(f1.x + b1.x, f1.y + b1.y);
                __half2 p3 = __floats2half2_rn(f1.z + b1.z, f1.w + b1.w);
                uint4 ov;
                ov.x = *(unsigned int*)&p0;
                ov.y = *(unsigned int*)&p1;
                ov.z = *(unsigned int*)&p2;
                ov.w = *(unsigned int*)&p3;
                *(uint4*)(C + (size_t)gr * FDIM + gc) = ov;
            }
        }
        __syncthreads();
    }
}

// ---------------- same GEMM, pre-split bf16 A planes, f16 C ----------------

__global__ __launch_bounds__(256) void gemm_pair_mfma_preA(
    const short* __restrict__ Ahi, const short* __restrict__ Alo,
    const short* __restrict__ B1h, const short* __restrict__ B1l,
    const float* __restrict__ bias1, __half* __restrict__ C1,
    const short* __restrict__ B2h, const short* __restrict__ B2l,
    const float* __restrict__ bias2, __half* __restrict__ C2,
    int M, int K) {
    __shared__ __align__(16) unsigned char smem[33792];
    uint4* AsHi = (uint4*)smem;
    uint4* AsLo = AsHi + 512;
    uint4* BsHi = AsLo + 512;
    uint4* BsLo = BsHi + 512;
    int tid = threadIdx.x;
    int lane = tid & 63;
    int wave = tid >> 6;
    int wm = wave & 1, wn = wave >> 1;
    int rowBase = blockIdx.x * 128;
    bool second = blockIdx.y >= 3;
    int colBase = (blockIdx.y - (second ? 3 : 0)) * 128;
    const short* Bh  = second ? B2h : B1h;
    const short* Bl  = second ? B2l : B1l;
    const float* bias = second ? bias2 : bias1;
    __half*      C    = second ? C2 : C1;

    float4v acc[4][4];
#pragma unroll
    for (int i = 0; i < 4; i++)
#pragma unroll
        for (int j = 0; j < 4; j++) acc[i][j] = (float4v){0.f, 0.f, 0.f, 0.f};

    for (int kt = 0; kt < K; kt += 32) {
#pragma unroll
        for (int i = 0; i < 2; i++) {
            int c = i * 256 + tid;
            int o = c >> 7, r = c & 127;
            int gr = rowBase + r;
            uint4 hv = make_uint4(0, 0, 0, 0), lv = hv;
            if (gr < M) {
                hv = *(const uint4*)(Ahi + (size_t)gr * K + kt + o * 8);
                lv = *(const uint4*)(Alo + (size_t)gr * K + kt + o * 8);
            }
            int slot = (r >> 4) * 64 + (o << 4) + (r & 15);
            AsHi[slot] = hv;
            AsLo[slot] = lv;
        }
#pragma unroll
        for (int i = 0; i < 4; i++) {
            int c = i * 256 + tid;
            int h = c >> 9, o = (c >> 7) & 3, n = c & 127;
            const short* src = h ? Bl : Bh;
            uint4 v = *(const uint4*)(src + (size_t)(colBase + n) * K + kt + o * 8);
            int slot = (n >> 4) * 64 + (o << 4) + (n & 15);
            if (h) BsLo[slot] = v; else BsHi[slot] = v;
        }
        __syncthreads();

        short8 ah[4], al[4], bh[4], blv[4];
#pragma unroll
        for (int i = 0; i < 4; i++) {
            ah[i]  = ((const short8*)AsHi)[(wm * 4 + i) * 64 + lane];
            al[i]  = ((const short8*)AsLo)[(wm * 4 + i) * 64 + lane];
            bh[i]  = ((const short8*)BsHi)[(wn * 4 + i) * 64 + lane];
            blv[i] = ((const short8*)BsLo)[(wn * 4 + i) * 64 + lane];
        }
#pragma unroll
        for (int i = 0; i < 4; i++)
#pragma unroll
            for (int j = 0; j < 4; j++) {
                acc[i][j] = __builtin_amdgcn_mfma_f32_16x16x32_bf16(ah[i], bh[j],  acc[i][j], 0, 0, 0);
                acc[i][j] = __builtin_amdgcn_mfma_f32_16x16x32_bf16(ah[i], blv[j], acc[i][j], 0, 0, 0);
                acc[i][j] = __builtin_amdgcn_mfma_f32_16x16x32_bf16(al[i], bh[j],  acc[i][j], 0, 0, 0);
            }
        __syncthreads();
    }

    float* Ct = (float*)smem;
    int cq = lane >> 4, cn = lane & 15;
#pragma unroll
    for (int ph = 0; ph < 2; ph++) {
        if (wm == ph) {
#pragma unroll
            for (int i = 0; i < 4; i++)
#pragma unroll
                for (int j = 0; j < 4; j++) {
                    int lr = i * 16 + cq * 4;
                    int lc = wn * 64 + j * 16 + cn;
#pragma unroll
                    for (int r = 0; r < 4; r++)
                        Ct[(lr + r) * 132 + lc] = acc[i][j][r];
                }
        }
        __syncthreads();
#pragma unroll
        for (int k = 0; k < 4; k++) {
            int o = k * 256 + tid;
            int lr = o >> 4;
            int oc = (o & 15) << 3;
            int gr = rowBase + ph * 64 + lr;
            if (gr < M) {
                float4 f0 = *(float4*)&Ct[lr * 132 + oc];
                float4 f1 = *(float4*)&Ct[lr * 132 + oc + 4];
                int gc = colBase + oc;
                float4 b0 = *(const float4*)(bias + gc);
                float4 b1 = *(const float4*)(bias + gc + 4);
                __half2 p0 = __floats2half2_rn(f0.x + b0.x, f0.y + b0.y);
                __half2 p1 = __floats2half2_rn(f0.z + b0.z, f0.w + b0.w);
                __half2 p2 = __floats2half2_rn(f1.x + b1.x, f1.y + b1.y);
                __half2 p3 = __floats2half2_rn(f1.z + b1.z, f1.w + b1.w);
                uint4 ov;
                ov.x = *(unsigned int*)&p0;
                ov.y = *(unsigned int*)&p1;
                ov.z = *(unsigned int*)&p2;
                ov.w = *(unsigned int*)&p3;
                *(uint4*)(C + (size_t)gr * FDIM + gc) = ov;
            }
        }
        __syncthreads();
    }
}

// ---------------- per-node GATv2 aggregation (one WAVE-sized block per node) ----------------

__global__ __launch_bounds__(64) void agg_kernel(const __half* __restrict__ xl,
                                                 const __half* __restrict__ xr,
                                                 const _Float16* __restrict__ att_h,
                                                 const float* __restrict__ bias,
                                                 const int* __restrict__ start,
                                                 const int* __restrict__ srcsOff,
                                                 short* __restrict__ houtHi,
                                                 short* __restrict__ houtLo,
                                                 const float* __restrict__ Wl,
                                                 const float* __restrict__ bl,
                                                 const float* __restrict__ Wr,
                                                 const float* __restrict__ br,
                                                 float* __restrict__ xloB,
                                                 float* __restrict__ xroB, int N) {
    int node = blockIdx.x;
    if (node >= N) return;
    int lane = threadIdx.x & 63;
    int hl = lane & 31;
    int half_ = lane >> 5;
    int cb = hl << 3;

    long nodeOff = (long)node * (FDIM * 2);
    hv2 xr2[6], at2[6];
    f32x4 acc[3];
    float s[3];
#pragma unroll
    for (int c = 0; c < 3; c++) {
        uint2 ur = *(const uint2*)((const char*)xr + nodeOff + c * 256 + cb);
        xr2[2*c]   = __builtin_bit_cast(hv2, ur.x);
        xr2[2*c+1] = __builtin_bit_cast(hv2, ur.y);
        uint2 ua = *(const uint2*)((const char*)att_h + c * 256 + cb);
        at2[2*c]   = __builtin_bit_cast(hv2, ua.x);
        at2[2*c+1] = __builtin_bit_cast(hv2, ua.y);
        acc[c] = (f32x4){0.f, 0.f, 0.f, 0.f};
        s[c] = 0.f;
    }
    const hv2 sl2 = {(_Float16)SLOPE, (_Float16)SLOPE};
    const char* xlb = (const char*)xl;

    int e0 = start[node], e1 = start[node + 1];

    for (int b = e0 - 1; b < e1; b += 4) {
        hv2 xa[2][6];
        float mask[2];
#pragma unroll
        for (int p = 0; p < 2; p++) {
            int myIdx = b + p * 2 + half_;
            int ic = min(myIdx, e1 - 1);
            long off = (ic < e0) ? nodeOff : (long)srcsOff[ic];
            mask[p] = (myIdx < e1) ? 0.f : -1e30f;
            const char* base = xlb + off + cb;
            uint2 u0 = *(const uint2*)(base);
            uint2 u1 = *(const uint2*)(base + 256);
            uint2 u2 = *(const uint2*)(base + 512);
            xa[p][0] = __builtin_bit_cast(hv2, u0.x); xa[p][1] = __builtin_bit_cast(hv2, u0.y);
            xa[p][2] = __builtin_bit_cast(hv2, u1.x); xa[p][3] = __builtin_bit_cast(hv2, u1.y);
            xa[p][4] = __builtin_bit_cast(hv2, u2.x); xa[p][5] = __builtin_bit_cast(hv2, u2.y);
        }
#pragma unroll
        for (int p = 0; p < 2; p++) {
            float pc[3];
#pragma unroll
            for (int c = 0; c < 3; c++) {
                hv2 t0 = xa[p][2*c]   + xr2[2*c];
                hv2 t1 = xa[p][2*c+1] + xr2[2*c+1];
                t0 = __builtin_elementwise_max(t0, t0 * sl2);
                t1 = __builtin_elementwise_max(t1, t1 * sl2);
                pc[c] = dot2acc(t1, at2[2*c+1], dot2acc(t0, at2[2*c], 0.f));
            }
#pragma unroll
            for (int st = 1; st <= 4; st <<= 1) {
                pc[0] += __shfl_xor(pc[0], st);
                pc[1] += __shfl_xor(pc[1], st);
                pc[2] += __shfl_xor(pc[2], st);
            }
#pragma unroll
            for (int c = 0; c < 3; c++) {
                float a = __expf(pc[c] + mask[p]);
                s[c] += a;
                acc[c].x = fmaf(a, (float)xa[p][2*c].x,   acc[c].x);
                acc[c].y = fmaf(a, (float)xa[p][2*c].y,   acc[c].y);
                acc[c].z = fmaf(a, (float)xa[p][2*c+1].x, acc[c].z);
                acc[c].w = fmaf(a, (float)xa[p][2*c+1].y, acc[c].w);
            }
        }
    }

    // merge halves
#pragma unroll
    for (int c = 0; c < 3; c++) {
        acc[c].x += __shfl_xor(acc[c].x, 32);
        acc[c].y += __shfl_xor(acc[c].y, 32);
        acc[c].z += __shfl_xor(acc[c].z, 32);
        acc[c].w += __shfl_xor(acc[c].w, 32);
        s[c] += __shfl_xor(s[c], 32);
    }
    f32x4 v[3];
#pragma unroll
    for (int c = 0; c < 3; c++) {
        float inv = 1.f / (s[c] + 1e-16f);
        f32x4 iv = {inv, inv, inv, inv};
        v[c] = acc[c] * iv;
    }
#pragma unroll
    for (int st = 8; st <= 16; st <<= 1) {
#pragma unroll
        for (int c = 0; c < 3; c++) {
            v[c].x += __shfl_xor(v[c].x, st);
            v[c].y += __shfl_xor(v[c].y, st);
            v[c].z += __shfl_xor(v[c].z, st);
            v[c].w += __shfl_xor(v[c].w, st);
        }
    }
    if (lane < 8) {
        f32x4 b4 = *(const f32x4*)(bias + (hl << 2));
        f32x4 o = (v[0] + v[1] + v[2]) * (f32x4){1.f/12.f, 1.f/12.f, 1.f/12.f, 1.f/12.f} + b4;
        o.x = o.x > 0.f ? o.x : expm1f(o.x);
        o.y = o.y > 0.f ? o.y : expm1f(o.y);
        o.z = o.z > 0.f ? o.z : expm1f(o.z);
        o.w = o.w > 0.f ? o.w : expm1f(o.w);
        if (houtHi) {
            float fs[4] = {o.x, o.y, o.z, o.w};
            unsigned int hb[4], lb[4];
#pragma unroll
            for (int t = 0; t < 4; t++) {
                hb[t] = bf16_rne(fs[t]);
                lb[t] = bf16_rne(fs[t] - __uint_as_float(hb[t] << 16));
            }
            uint2 hp, lp;
            hp.x = hb[0] | (hb[1] << 16); hp.y = hb[2] | (hb[3] << 16);
            lp.x = lb[0] | (lb[1] << 16); lp.y = lb[2] | (lb[3] << 16);
            *(uint2*)(houtHi + (size_t)node * 32 + (hl << 2)) = hp;
            *(uint2*)(houtLo + (size_t)node * 32 + (hl << 2)) = lp;
        }
        if (Wl) {
            f32x4 wl0 = *(const f32x4*)(Wl + (hl << 3));
            f32x4 wl1 = *(const f32x4*)(Wl + (hl << 3) + 4);
            f32x4 wr0 = *(const f32x4*)(Wr + (hl << 3));
            f32x4 wr1 = *(const f32x4*)(Wr + (hl << 3) + 4);
            float l0 = o.x * wl0.x + o.y * wl0.z + o.z * wl1.x + o.w * wl1.z;
            float l1 = o.x * wl0.y + o.y * wl0.w + o.z * wl1.y + o.w * wl1.w;
            float r0 = o.x * wr0.x + o.y * wr0.z + o.z * wr1.x + o.w * wr1.z;
            float r1 = o.x * wr0.y + o.y * wr0.w + o.z * wr1.y + o.w * wr1.w;
#pragma unroll
            for (int st = 1; st <= 4; st <<= 1) {
                l0 += __shfl_xor(l0, st); l1 += __shfl_xor(l1, st);
                r0 += __shfl_xor(r0, st); r1 += __shfl_xor(r1, st);
            }
            if (hl == 0) {
                xloB[2 * node]     = l0 + bl[0];
                xloB[2 * node + 1] = l1 + bl[1];
                xroB[2 * node]     = r0 + br[0];
                xroB[2 * node + 1] = r1 + br[1];
            }
        }
    }
}

// ---------------- output aggregation (heads=1, C=2): 8 lanes per node ----------------
// lane j of the 8-lane group strides edges by 8; shuffle-reduce s/acc over the group.

__global__ __launch_bounds__(256) void out_agg_kernel(const float* __restrict__ xlo,
                                                      const float* __restrict__ xro,
                                                      const float* __restrict__ atto,
                                                      const float* __restrict__ biaso,
                                                      const int* __restrict__ start,
                                                      const int* __restrict__ srcs,
                                                      float* __restrict__ out, int N) {
    int g = (blockIdx.x * blockDim.x + threadIdx.x) >> 3;   // node
    int j = threadIdx.x & 7;
    if (g >= N) return;
    float a0 = atto[0], a1 = atto[1];
    float xr0 = xro[2 * g], xr1 = xro[2 * g + 1];
    float s = 0.f, acc0 = 0.f, acc1 = 0.f;
    int e0 = start[g], e1 = start[g + 1];
    for (int idx = e0 - 1 + j; idx < e1; idx += 8) {
        int jj = (idx < e0) ? g : srcs[idx];
        float x0 = xlo[2 * jj], x1 = xlo[2 * jj + 1];
        float t0 = x0 + xr0, t1 = x1 + xr1;
        t0 = fmaxf(t0, SLOPE * t0);
        t1 = fmaxf(t1, SLOPE * t1);
        float L = a0 * t0 + a1 * t1;
        float a = __expf(L);
        s += a;
        acc0 = fmaf(a, x0, acc0);
        acc1 = fmaf(a, x1, acc1);
    }
#pragma unroll
    for (int st = 1; st <= 4; st <<= 1) {
        s    += __shfl_xor(s, st);
        acc0 += __shfl_xor(acc0, st);
        acc1 += __shfl_xor(acc1, st);
    }
    if (j == 0) {
        float inv = 1.0f / (s + 1e-16f);
        out[2 * g]     = acc0 * inv + biaso[0];
        out[2 * g + 1] = acc1 * inv + biaso[1];
    }
}

// ---------------- launch ----------------

extern "C" void kernel_launch(void* const* d_in, const int* in_sizes, int n_in,
                              void* d_out, int out_size, void* d_ws, size_t ws_size,
                              hipStream_t stream) {
    const float* x    = (const float*)d_in[0];
    const int*   ei   = (const int*)d_in[1];
    const float* Wl0  = (const float*)d_in[2];
    const float* bl0  = (const float*)d_in[3];
    const float* Wr0  = (const float*)d_in[4];
    const float* br0  = (const float*)d_in[5];
    const float* att0 = (const float*)d_in[6];
    const float* bias0= (const float*)d_in[7];
    const float* Wl1  = (const float*)d_in[8];
    const float* bl1  = (const float*)d_in[9];
    const float* Wr1  = (const float*)d_in[10];
    const float* br1  = (const float*)d_in[11];
    const float* att1 = (const float*)d_in[12];
    const float* bias1= (const float*)d_in[13];
    const float* Wlo  = (const float*)d_in[14];
    const float* blo  = (const float*)d_in[15];
    const float* Wro  = (const float*)d_in[16];
    const float* bro  = (const float*)d_in[17];
    const float* atto = (const float*)d_in[18];
    const float* biaso= (const float*)d_in[19];

    const int N = in_sizes[0] / IN_DIM;
    const int E = in_sizes[1] / 2;

    char* ws = (char*)d_ws;
    size_t off = 0;
    auto take = [&](size_t bytes) -> char* {
        char* p = ws + off;
        off += (bytes + 255) & ~(size_t)255;
        return p;
    };
    __half* xlf = (__half*)take((size_t)N * FDIM * 2);
    __half* xrf = (__half*)take((size_t)N * FDIM * 2);
    float* xloB = (float*)take((size_t)N * 2 * 4);
    float* xroB = (float*)take((size_t)N * 2 * 4);
    int* cnt    = (int*)take((size_t)N * 4);
    int* startA = (int*)take((size_t)(N + 1) * 4);
    int* cursor = (int*)take((size_t)N * 4);
    int* srcs   = (int*)take((size_t)E * 4);
    int* srcsOff= (int*)take((size_t)E * 4);
    int  nb     = (N + 255) / 256;
    int* partials = (int*)take((size_t)nb * 4);
    short* Bl0h = (short*)take((size_t)FDIM * IN_DIM * 2);
    short* Bl0l = (short*)take((size_t)FDIM * IN_DIM * 2);
    short* Br0h = (short*)take((size_t)FDIM * IN_DIM * 2);
    short* Br0l = (short*)take((size_t)FDIM * IN_DIM * 2);
    short* Bl1h = (short*)take((size_t)FDIM * HID * 2);
    short* Bl1l = (short*)take((size_t)FDIM * HID * 2);
    short* Br1h = (short*)take((size_t)FDIM * HID * 2);
    short* Br1l = (short*)take((size_t)FDIM * HID * 2);
    short* h0h  = (short*)take((size_t)N * HID * 2);
    short* h0l  = (short*)take((size_t)N * HID * 2);
    _Float16* attH = (_Float16*)take((size_t)768 * 2);

    const int* esrc = ei;
    const int* edst = ei + E;

    // merged prep (weights + att)
    prep_all<<<(62208 + 255) / 256, 256, 0, stream>>>(Wl0, Wr0, Wl1, Wr1, att0, att1,
                                                      Bl0h, Bl0l, Br0h, Br0l,
                                                      Bl1h, Bl1l, Br1h, Br1l, attH);

    // CSR build (by destination)
    hipMemsetAsync(cnt, 0, (size_t)N * 4, stream);
    hist_kernel<<<(E + 255) / 256, 256, 0, stream>>>(edst, cnt, E);
    scan_partial_kernel<<<nb, 256, 0, stream>>>(cnt, partials, N);
    scan_top_kernel<<<1, 1024, 0, stream>>>(partials, nb);
    scan_final_kernel<<<nb, 256, 0, stream>>>(cnt, partials, startA, cursor, N);
    scatter_kernel<<<(E + 255) / 256, 256, 0, stream>>>(esrc, edst, cursor, srcs, srcsOff, E);

    dim3 ggrid((N + 127) / 128, 6);
    // layer 0
    gemm_pair_mfma_f32A<<<ggrid, 256, 0, stream>>>(x, Bl0h, Bl0l, bl0, xlf, Br0h, Br0l, br0, xrf, N, IN_DIM);
    agg_kernel<<<N, 64, 0, stream>>>(xlf, xrf, attH, bias0, startA, srcsOff,
                                     h0h, h0l, nullptr, nullptr, nullptr, nullptr,
                                     nullptr, nullptr, N);
    // layer 1
    gemm_pair_mfma_preA<<<ggrid, 256, 0, stream>>>(h0h, h0l, Bl1h, Bl1l, bl1, xlf, Br1h, Br1l, br1, xrf, N, HID);
    agg_kernel<<<N, 64, 0, stream>>>(xlf, xrf, attH + 384, bias1, startA, srcsOff,
                                     nullptr, nullptr, Wlo, blo, Wro, bro,
                                     xloB, xroB, N);
    // output aggregation (8 lanes/node)
    out_agg_kernel<<<((size_t)N * 8 + 255) / 256, 256, 0, stream>>>(xloB, xroB, atto, biaso, startA, srcs, (float*)d_out, N);
}

// Round 16
// 382.128 us; speedup vs baseline: 1.1383x; 1.0118x over previous
//
#include <hip/hip_runtime.h>
#include <hip/hip_fp16.h>
#include <math.h>

#define IN_DIM 128
#define HID 32
#define HEADS 12
#define FDIM (HEADS*HID)   // 384
#define SLOPE 0.2f

typedef __attribute__((ext_vector_type(8))) short short8;
typedef __attribute__((ext_vector_type(4))) float float4v;
typedef __attribute__((ext_vector_type(4))) float f32x4;
typedef _Float16 hv2 __attribute__((ext_vector_type(2)));

__device__ __forceinline__ float dot2acc(hv2 a, hv2 b, float c) {
#if __has_builtin(__builtin_amdgcn_fdot2)
    return __builtin_amdgcn_fdot2(a, b, c, false);
#else
    return c + (float)a.x * (float)b.x + (float)a.y * (float)b.y;
#endif
}

// async global->LDS 16B per lane; LDS dst is wave-uniform base + lane*16
__device__ __forceinline__ void async_cp16(const void* g, void* l) {
    __builtin_amdgcn_global_load_lds(
        (const __attribute__((address_space(1))) void*)g,
        (__attribute__((address_space(3))) void*)l, 16, 0, 0);
}

// ---------------- CSR build ----------------

__global__ void hist_kernel(const int* __restrict__ dst, int* __restrict__ cnt, int E) {
    int e = blockIdx.x * blockDim.x + threadIdx.x;
    if (e < E) atomicAdd(&cnt[dst[e]], 1);
}

__global__ __launch_bounds__(256) void scan_partial_kernel(const int* __restrict__ cnt,
                                                           int* __restrict__ partials, int n) {
    int i = blockIdx.x * 256 + threadIdx.x;
    int v = (i < n) ? cnt[i] : 0;
#pragma unroll
    for (int off = 1; off < 64; off <<= 1) v += __shfl_xor(v, off);
    __shared__ int sh[4];
    if ((threadIdx.x & 63) == 0) sh[threadIdx.x >> 6] = v;
    __syncthreads();
    if (threadIdx.x == 0) partials[blockIdx.x] = sh[0] + sh[1] + sh[2] + sh[3];
}

__global__ __launch_bounds__(1024) void scan_top_kernel(int* __restrict__ partials, int nb) {
    __shared__ int sh[1024];
    int t = threadIdx.x;
    int v = (t < nb) ? partials[t] : 0;
    sh[t] = v;
    __syncthreads();
    for (int off = 1; off < 1024; off <<= 1) {
        int u = (t >= off) ? sh[t - off] : 0;
        __syncthreads();
        sh[t] += u;
        __syncthreads();
    }
    if (t < nb) partials[t] = sh[t] - v;   // exclusive
}

__global__ __launch_bounds__(256) void scan_final_kernel(const int* __restrict__ cnt,
                                                         const int* __restrict__ partials,
                                                         int* __restrict__ start,
                                                         int* __restrict__ cursor, int n) {
    __shared__ int sh[256];
    int t = threadIdx.x;
    int i = blockIdx.x * 256 + t;
    int v = (i < n) ? cnt[i] : 0;
    sh[t] = v;
    __syncthreads();
    for (int off = 1; off < 256; off <<= 1) {
        int u = (t >= off) ? sh[t - off] : 0;
        __syncthreads();
        sh[t] += u;
        __syncthreads();
    }
    int ex = sh[t] - v + partials[blockIdx.x];
    if (i < n) {
        start[i] = ex;
        cursor[i] = ex;
        if (i == n - 1) start[n] = ex + v;
    }
}

__global__ void scatter_kernel(const int* __restrict__ src, const int* __restrict__ dst,
                               int* __restrict__ cursor, int* __restrict__ srcs,
                               int* __restrict__ srcsOff, int E) {
    int e = blockIdx.x * blockDim.x + threadIdx.x;
    if (e < E) {
        int d = dst[e];
        int pos = atomicAdd(&cursor[d], 1);
        int s = src[e];
        srcs[pos] = s;
        srcsOff[pos] = s * (FDIM * 2);   // byte offset into f16 feature rows
    }
}

// ---------------- bf16 split helpers ----------------

__device__ __forceinline__ unsigned int bf16_rne(float f) {
    unsigned int u = __float_as_uint(f);
    return (u + 0x7FFFu + ((u >> 16) & 1u)) >> 16;
}

// ---------------- merged prep: weights (both layers) + att f16 ----------------

__global__ void prep_all(const float* __restrict__ Wl0, const float* __restrict__ Wr0,
                         const float* __restrict__ Wl1, const float* __restrict__ Wr1,
                         const float* __restrict__ a0, const float* __restrict__ a1,
                         short* __restrict__ Bl0h, short* __restrict__ Bl0l,
                         short* __restrict__ Br0h, short* __restrict__ Br0l,
                         short* __restrict__ Bl1h, short* __restrict__ Bl1l,
                         short* __restrict__ Br1h, short* __restrict__ Br1l,
                         _Float16* __restrict__ attH) {
    int idx = blockIdx.x * 256 + threadIdx.x;
    if (idx < 49152) {
        int k = idx / 384, n = idx - k * 384;
        float w1 = Wl0[idx], w2 = Wr0[idx];
        unsigned int h1 = bf16_rne(w1);
        unsigned int l1 = bf16_rne(w1 - __uint_as_float(h1 << 16));
        unsigned int h2 = bf16_rne(w2);
        unsigned int l2 = bf16_rne(w2 - __uint_as_float(h2 << 16));
        Bl0h[n * 128 + k] = (short)h1;  Bl0l[n * 128 + k] = (short)l1;
        Br0h[n * 128 + k] = (short)h2;  Br0l[n * 128 + k] = (short)l2;
    } else if (idx < 61440) {
        int i2 = idx - 49152;
        int k = i2 / 384, n = i2 - k * 384;
        float w1 = Wl1[i2], w2 = Wr1[i2];
        unsigned int h1 = bf16_rne(w1);
        unsigned int l1 = bf16_rne(w1 - __uint_as_float(h1 << 16));
        unsigned int h2 = bf16_rne(w2);
        unsigned int l2 = bf16_rne(w2 - __uint_as_float(h2 << 16));
        Bl1h[n * 32 + k] = (short)h1;  Bl1l[n * 32 + k] = (short)l1;
        Br1h[n * 32 + k] = (short)h2;  Br1l[n * 32 + k] = (short)l2;
    } else if (idx < 62208) {
        int i2 = idx - 61440;
        attH[i2] = (_Float16)((i2 < 384) ? a0[i2] : a1[i2 - 384]);
    }
}

// ---------------- input prep: x fp32 -> bf16 hi/lo planes (float4 vectorized) ----------------

__global__ void conv_x_kernel(const float* __restrict__ A, short* __restrict__ Ah,
                              short* __restrict__ Al, int total4) {
    int i = blockIdx.x * 256 + threadIdx.x;
    if (i >= total4) return;
    float4 v = ((const float4*)A)[i];
    float fs[4] = {v.x, v.y, v.z, v.w};
    unsigned int hb[4], lb[4];
#pragma unroll
    for (int t = 0; t < 4; t++) {
        hb[t] = bf16_rne(fs[t]);
        lb[t] = bf16_rne(fs[t] - __uint_as_float(hb[t] << 16));
    }
    uint2 hp, lp;
    hp.x = hb[0] | (hb[1] << 16); hp.y = hb[2] | (hb[3] << 16);
    lp.x = lb[0] | (lb[1] << 16); lp.y = lb[2] | (lb[3] << 16);
    ((uint2*)Ah)[i] = hp;
    ((uint2*)Al)[i] = lp;
}

// ---------------- bf16x3 MFMA GEMM pair, async global->LDS staging ----------------
// C{1,2}[M x 384] = A @ B{1,2} + bias via Ahi.Bhi + Ahi.Blo + Alo.Bhi.
// A planes row-major [M][K] bf16; B planes transposed [384][K] bf16; K mult of 32.
// Staging: 2048 16B chunks/k-tile via global_load_lds (8 per thread). LDS in fragment
// order; chunk q of wave w lands at ldsOff = q*4096 + w*1024 + lane*16 (wave-uniform
// base per the m104 constraint), holding X[row=((q&1)*4+w)*16+(lane&15)][koct=lane>>4].
// Buffers: AsHi | AsLo | BsHi | BsLo at 8KB each. OOB rows read valid ws garbage ->
// pollute only unstored C rows. Epilogue: LDS-transpose coalesced f16 store.

__global__ __launch_bounds__(256) void gemm_pair_async(
    const short* __restrict__ Ahi, const short* __restrict__ Alo,
    const short* __restrict__ B1h, const short* __restrict__ B1l,
    const float* __restrict__ bias1, __half* __restrict__ C1,
    const short* __restrict__ B2h, const short* __restrict__ B2l,
    const float* __restrict__ bias2, __half* __restrict__ C2,
    int M, int K) {
    __shared__ __align__(16) unsigned char smem[33792];
    int tid = threadIdx.x;
    int lane = tid & 63;
    int wave = tid >> 6;
    int wm = wave & 1, wn = wave >> 1;
    int rowBase = blockIdx.x * 128;
    bool second = blockIdx.y >= 3;
    int colBase = (blockIdx.y - (second ? 3 : 0)) * 128;
    const short* Bh  = second ? B2h : B1h;
    const short* Bl  = second ? B2l : B1l;
    const float* bias = second ? bias2 : bias1;
    __half*      C    = second ? C2 : C1;

    const short8* AsHi = (const short8*)smem;
    const short8* AsLo = (const short8*)(smem + 8192);
    const short8* BsHi = (const short8*)(smem + 16384);
    const short8* BsLo = (const short8*)(smem + 24576);

    // per-lane global sources + wave-uniform LDS destinations for the 8 chunks
    const short* gsrc[8];
    void* ldst[8];
#pragma unroll
    for (int q = 0; q < 8; q++) {
        int t  = (q & 1) * 4 + wave;          // fragment tile 0..7
        int rc = t * 16 + (lane & 15);        // row (A) / col (B)
        int ko = (lane >> 4) * 8;             // k-octet start
        const short* base = (q < 2) ? Ahi : (q < 4) ? Alo : (q < 6) ? Bh : Bl;
        int rb = (q < 4) ? rowBase : colBase;
        gsrc[q] = base + (long)(rb + rc) * K + ko;
        ldst[q] = (void*)(smem + q * 4096 + wave * 1024);
    }

    float4v acc[4][4];
#pragma unroll
    for (int i = 0; i < 4; i++)
#pragma unroll
        for (int j = 0; j < 4; j++) acc[i][j] = (float4v){0.f, 0.f, 0.f, 0.f};

    for (int kt = 0; kt < K; kt += 32) {
#pragma unroll
        for (int q = 0; q < 8; q++) {
            async_cp16(gsrc[q], ldst[q]);
            gsrc[q] += 32;
        }
        __syncthreads();   // drains vmcnt(0): async loads landed; all waves synced

        short8 ah[4], al[4], bh[4], blv[4];
#pragma unroll
        for (int i = 0; i < 4; i++) {
            ah[i]  = AsHi[(wm * 4 + i) * 64 + lane];
            al[i]  = AsLo[(wm * 4 + i) * 64 + lane];
            bh[i]  = BsHi[(wn * 4 + i) * 64 + lane];
            blv[i] = BsLo[(wn * 4 + i) * 64 + lane];
        }
#pragma unroll
        for (int i = 0; i < 4; i++)
#pragma unroll
            for (int j = 0; j < 4; j++) {
                acc[i][j] = __builtin_amdgcn_mfma_f32_16x16x32_bf16(ah[i], bh[j],  acc[i][j], 0, 0, 0);
                acc[i][j] = __builtin_amdgcn_mfma_f32_16x16x32_bf16(ah[i], blv[j], acc[i][j], 0, 0, 0);
                acc[i][j] = __builtin_amdgcn_mfma_f32_16x16x32_bf16(al[i], bh[j],  acc[i][j], 0, 0, 0);
            }
        __syncthreads();   // protect LDS from next tile's async writes
    }

    // coalesced epilogue via LDS transpose (C/D layout: col=lane&15, row=(lane>>4)*4+reg)
    float* Ct = (float*)smem;
    int cq = lane >> 4, cn = lane & 15;
#pragma unroll
    for (int ph = 0; ph < 2; ph++) {
        if (wm == ph) {
#pragma unroll
            for (int i = 0; i < 4; i++)
#pragma unroll
                for (int j = 0; j < 4; j++) {
                    int lr = i * 16 + cq * 4;
                    int lc = wn * 64 + j * 16 + cn;
#pragma unroll
                    for (int r = 0; r < 4; r++)
                        Ct[(lr + r) * 132 + lc] = acc[i][j][r];
                }
        }
        __syncthreads();
#pragma unroll
        for (int k = 0; k < 4; k++) {
            int o = k * 256 + tid;
            int lr = o >> 4;
            int oc = (o & 15) << 3;
            int gr = rowBase + ph * 64 + lr;
            if (gr < M) {
                float4 f0 = *(float4*)&Ct[lr * 132 + oc];
                float4 f1 = *(float4*)&Ct[lr * 132 + oc + 4];
                int gc = colBase + oc;
                float4 b0 = *(const float4*)(bias + gc);
                float4 b1 = *(const float4*)(bias + gc + 4);
                __half2 p0 = __floats2half2_rn(f0.x + b0.x, f0.y + b0.y);
                __half2 p1 = __floats2half2_rn(f0.z + b0.z, f0.w + b0.w);
                __half2 p2 = __floats2half2_rn(f1.x + b1.x, f1.y + b1.y);
                __half2 p3 = __floats2half2_rn(f1.z + b1.z, f1.w + b1.w);
                uint4 ov;
                ov.x = *(unsigned int*)&p0;
                ov.y = *(unsigned int*)&p1;
                ov.z = *(unsigned int*)&p2;
                ov.w = *(unsigned int*)&p3;
                *(uint4*)(C + (size_t)gr * FDIM + gc) = ov;
            }
        }
        __syncthreads();
    }
}

// ---------------- per-node GATv2 aggregation (one WAVE-sized block per node) ----------------

__global__ __launch_bounds__(64) void agg_kernel(const __half* __restrict__ xl,
                                                 const __half* __restrict__ xr,
                                                 const _Float16* __restrict__ att_h,
                                                 const float* __restrict__ bias,
                                                 const int* __restrict__ start,
                                                 const int* __restrict__ srcsOff,
                                                 short* __restrict__ houtHi,
                                                 short* __restrict__ houtLo,
                                                 const float* __restrict__ Wl,
                                                 const float* __restrict__ bl,
                                                 const float* __restrict__ Wr,
                                                 const float* __restrict__ br,
                                                 float* __restrict__ xloB,
                                                 float* __restrict__ xroB, int N) {
    int node = blockIdx.x;
    if (node >= N) return;
    int lane = threadIdx.x & 63;
    int hl = lane & 31;
    int half_ = lane >> 5;
    int cb = hl << 3;

    long nodeOff = (long)node * (FDIM * 2);
    hv2 xr2[6], at2[6];
    f32x4 acc[3];
    float s[3];
#pragma unroll
    for (int c = 0; c < 3; c++) {
        uint2 ur = *(const uint2*)((const char*)xr + nodeOff + c * 256 + cb);
        xr2[2*c]   = __builtin_bit_cast(hv2, ur.x);
        xr2[2*c+1] = __builtin_bit_cast(hv2, ur.y);
        uint2 ua = *(const uint2*)((const char*)att_h + c * 256 + cb);
        at2[2*c]   = __builtin_bit_cast(hv2, ua.x);
        at2[2*c+1] = __builtin_bit_cast(hv2, ua.y);
        acc[c] = (f32x4){0.f, 0.f, 0.f, 0.f};
        s[c] = 0.f;
    }
    const hv2 sl2 = {(_Float16)SLOPE, (_Float16)SLOPE};
    const char* xlb = (const char*)xl;

    int e0 = start[node], e1 = start[node + 1];

    for (int b = e0 - 1; b < e1; b += 4) {
        hv2 xa[2][6];
        float mask[2];
#pragma unroll
        for (int p = 0; p < 2; p++) {
            int myIdx = b + p * 2 + half_;
            int ic = min(myIdx, e1 - 1);
            long off = (ic < e0) ? nodeOff : (long)srcsOff[ic];
            mask[p] = (myIdx < e1) ? 0.f : -1e30f;
            const char* base = xlb + off + cb;
            uint2 u0 = *(const uint2*)(base);
            uint2 u1 = *(const uint2*)(base + 256);
            uint2 u2 = *(const uint2*)(base + 512);
            xa[p][0] = __builtin_bit_cast(hv2, u0.x); xa[p][1] = __builtin_bit_cast(hv2, u0.y);
            xa[p][2] = __builtin_bit_cast(hv2, u1.x); xa[p][3] = __builtin_bit_cast(hv2, u1.y);
            xa[p][4] = __builtin_bit_cast(hv2, u2.x); xa[p][5] = __builtin_bit_cast(hv2, u2.y);
        }
#pragma unroll
        for (int p = 0; p < 2; p++) {
            float pc[3];
#pragma unroll
            for (int c = 0; c < 3; c++) {
                hv2 t0 = xa[p][2*c]   + xr2[2*c];
                hv2 t1 = xa[p][2*c+1] + xr2[2*c+1];
                t0 = __builtin_elementwise_max(t0, t0 * sl2);
                t1 = __builtin_elementwise_max(t1, t1 * sl2);
                pc[c] = dot2acc(t1, at2[2*c+1], dot2acc(t0, at2[2*c], 0.f));
            }
#pragma unroll
            for (int st = 1; st <= 4; st <<= 1) {
                pc[0] += __shfl_xor(pc[0], st);
                pc[1] += __shfl_xor(pc[1], st);
                pc[2] += __shfl_xor(pc[2], st);
            }
#pragma unroll
            for (int c = 0; c < 3; c++) {
                float a = __expf(pc[c] + mask[p]);
                s[c] += a;
                acc[c].x = fmaf(a, (float)xa[p][2*c].x,   acc[c].x);
                acc[c].y = fmaf(a, (float)xa[p][2*c].y,   acc[c].y);
                acc[c].z = fmaf(a, (float)xa[p][2*c+1].x, acc[c].z);
                acc[c].w = fmaf(a, (float)xa[p][2*c+1].y, acc[c].w);
            }
        }
    }

    // merge halves
#pragma unroll
    for (int c = 0; c < 3; c++) {
        acc[c].x += __shfl_xor(acc[c].x, 32);
        acc[c].y += __shfl_xor(acc[c].y, 32);
        acc[c].z += __shfl_xor(acc[c].z, 32);
        acc[c].w += __shfl_xor(acc[c].w, 32);
        s[c] += __shfl_xor(s[c], 32);
    }
    f32x4 v[3];
#pragma unroll
    for (int c = 0; c < 3; c++) {
        float inv = 1.f / (s[c] + 1e-16f);
        f32x4 iv = {inv, inv, inv, inv};
        v[c] = acc[c] * iv;
    }
#pragma unroll
    for (int st = 8; st <= 16; st <<= 1) {
#pragma unroll
        for (int c = 0; c < 3; c++) {
            v[c].x += __shfl_xor(v[c].x, st);
            v[c].y += __shfl_xor(v[c].y, st);
            v[c].z += __shfl_xor(v[c].z, st);
            v[c].w += __shfl_xor(v[c].w, st);
        }
    }
    if (lane < 8) {
        f32x4 b4 = *(const f32x4*)(bias + (hl << 2));
        f32x4 o = (v[0] + v[1] + v[2]) * (f32x4){1.f/12.f, 1.f/12.f, 1.f/12.f, 1.f/12.f} + b4;
        o.x = o.x > 0.f ? o.x : expm1f(o.x);
        o.y = o.y > 0.f ? o.y : expm1f(o.y);
        o.z = o.z > 0.f ? o.z : expm1f(o.z);
        o.w = o.w > 0.f ? o.w : expm1f(o.w);
        if (houtHi) {
            float fs[4] = {o.x, o.y, o.z, o.w};
            unsigned int hb[4], lb[4];
#pragma unroll
            for (int t = 0; t < 4; t++) {
                hb[t] = bf16_rne(fs[t]);
                lb[t] = bf16_rne(fs[t] - __uint_as_float(hb[t] << 16));
            }
            uint2 hp, lp;
            hp.x = hb[0] | (hb[1] << 16); hp.y = hb[2] | (hb[3] << 16);
            lp.x = lb[0] | (lb[1] << 16); lp.y = lb[2] | (lb[3] << 16);
            *(uint2*)(houtHi + (size_t)node * 32 + (hl << 2)) = hp;
            *(uint2*)(houtLo + (size_t)node * 32 + (hl << 2)) = lp;
        }
        if (Wl) {
            f32x4 wl0 = *(const f32x4*)(Wl + (hl << 3));
            f32x4 wl1 = *(const f32x4*)(Wl + (hl << 3) + 4);
            f32x4 wr0 = *(const f32x4*)(Wr + (hl << 3));
            f32x4 wr1 = *(const f32x4*)(Wr + (hl << 3) + 4);
            float l0 = o.x * wl0.x + o.y * wl0.z + o.z * wl1.x + o.w * wl1.z;
            float l1 = o.x * wl0.y + o.y * wl0.w + o.z * wl1.y + o.w * wl1.w;
            float r0 = o.x * wr0.x + o.y * wr0.z + o.z * wr1.x + o.w * wr1.z;
            float r1 = o.x * wr0.y + o.y * wr0.w + o.z * wr1.y + o.w * wr1.w;
#pragma unroll
            for (int st = 1; st <= 4; st <<= 1) {
                l0 += __shfl_xor(l0, st); l1 += __shfl_xor(l1, st);
                r0 += __shfl_xor(r0, st); r1 += __shfl_xor(r1, st);
            }
            if (hl == 0) {
                xloB[2 * node]     = l0 + bl[0];
                xloB[2 * node + 1] = l1 + bl[1];
                xroB[2 * node]     = r0 + br[0];
                xroB[2 * node + 1] = r1 + br[1];
            }
        }
    }
}

// ---------------- output aggregation (heads=1, C=2): 8 lanes per node ----------------

__global__ __launch_bounds__(256) void out_agg_kernel(const float* __restrict__ xlo,
                                                      const float* __restrict__ xro,
                                                      const float* __restrict__ atto,
                                                      const float* __restrict__ biaso,
                                                      const int* __restrict__ start,
                                                      const int* __restrict__ srcs,
                                                      float* __restrict__ out, int N) {
    int g = (blockIdx.x * blockDim.x + threadIdx.x) >> 3;   // node
    int j = threadIdx.x & 7;
    if (g >= N) return;
    float a0 = atto[0], a1 = atto[1];
    float xr0 = xro[2 * g], xr1 = xro[2 * g + 1];
    float s = 0.f, acc0 = 0.f, acc1 = 0.f;
    int e0 = start[g], e1 = start[g + 1];
    for (int idx = e0 - 1 + j; idx < e1; idx += 8) {
        int jj = (idx < e0) ? g : srcs[idx];
        float x0 = xlo[2 * jj], x1 = xlo[2 * jj + 1];
        float t0 = x0 + xr0, t1 = x1 + xr1;
        t0 = fmaxf(t0, SLOPE * t0);
        t1 = fmaxf(t1, SLOPE * t1);
        float L = a0 * t0 + a1 * t1;
        float a = __expf(L);
        s += a;
        acc0 = fmaf(a, x0, acc0);
        acc1 = fmaf(a, x1, acc1);
    }
#pragma unroll
    for (int st = 1; st <= 4; st <<= 1) {
        s    += __shfl_xor(s, st);
        acc0 += __shfl_xor(acc0, st);
        acc1 += __shfl_xor(acc1, st);
    }
    if (j == 0) {
        float inv = 1.0f / (s + 1e-16f);
        out[2 * g]     = acc0 * inv + biaso[0];
        out[2 * g + 1] = acc1 * inv + biaso[1];
    }
}

// ---------------- launch ----------------

extern "C" void kernel_launch(void* const* d_in, const int* in_sizes, int n_in,
                              void* d_out, int out_size, void* d_ws, size_t ws_size,
                              hipStream_t stream) {
    const float* x    = (const float*)d_in[0];
    const int*   ei   = (const int*)d_in[1];
    const float* Wl0  = (const float*)d_in[2];
    const float* bl0  = (const float*)d_in[3];
    const float* Wr0  = (const float*)d_in[4];
    const float* br0  = (const float*)d_in[5];
    const float* att0 = (const float*)d_in[6];
    const float* bias0= (const float*)d_in[7];
    const float* Wl1  = (const float*)d_in[8];
    const float* bl1  = (const float*)d_in[9];
    const float* Wr1  = (const float*)d_in[10];
    const float* br1  = (const float*)d_in[11];
    const float* att1 = (const float*)d_in[12];
    const float* bias1= (const float*)d_in[13];
    const float* Wlo  = (const float*)d_in[14];
    const float* blo  = (const float*)d_in[15];
    const float* Wro  = (const float*)d_in[16];
    const float* bro  = (const float*)d_in[17];
    const float* atto = (const float*)d_in[18];
    const float* biaso= (const float*)d_in[19];

    const int N = in_sizes[0] / IN_DIM;
    const int E = in_sizes[1] / 2;

    char* ws = (char*)d_ws;
    size_t off = 0;
    auto take = [&](size_t bytes) -> char* {
        char* p = ws + off;
        off += (bytes + 255) & ~(size_t)255;
        return p;
    };
    __half* xlf = (__half*)take((size_t)N * FDIM * 2);
    __half* xrf = (__half*)take((size_t)N * FDIM * 2);
    float* xloB = (float*)take((size_t)N * 2 * 4);
    float* xroB = (float*)take((size_t)N * 2 * 4);
    int* cnt    = (int*)take((size_t)N * 4);
    int* startA = (int*)take((size_t)(N + 1) * 4);
    int* cursor = (int*)take((size_t)N * 4);
    int* srcs   = (int*)take((size_t)E * 4);
    int* srcsOff= (int*)take((size_t)E * 4);
    int  nb     = (N + 255) / 256;
    int* partials = (int*)take((size_t)nb * 4);
    short* Bl0h = (short*)take((size_t)FDIM * IN_DIM * 2);
    short* Bl0l = (short*)take((size_t)FDIM * IN_DIM * 2);
    short* Br0h = (short*)take((size_t)FDIM * IN_DIM * 2);
    short* Br0l = (short*)take((size_t)FDIM * IN_DIM * 2);
    short* Bl1h = (short*)take((size_t)FDIM * HID * 2);
    short* Bl1l = (short*)take((size_t)FDIM * HID * 2);
    short* Br1h = (short*)take((size_t)FDIM * HID * 2);
    short* Br1l = (short*)take((size_t)FDIM * HID * 2);
    short* xh   = (short*)take((size_t)N * IN_DIM * 2);
    short* xlo_ = (short*)take((size_t)N * IN_DIM * 2);
    short* h0h  = (short*)take((size_t)N * HID * 2);
    short* h0l  = (short*)take((size_t)N * HID * 2);
    _Float16* attH = (_Float16*)take((size_t)768 * 2);
    (void)take(32768);   // slack: OOB tile rows read valid ws memory

    const int* esrc = ei;
    const int* edst = ei + E;

    // merged prep (weights + att) + input bf16 split
    prep_all<<<(62208 + 255) / 256, 256, 0, stream>>>(Wl0, Wr0, Wl1, Wr1, att0, att1,
                                                      Bl0h, Bl0l, Br0h, Br0l,
                                                      Bl1h, Bl1l, Br1h, Br1l, attH);
    conv_x_kernel<<<((N * IN_DIM / 4) + 255) / 256, 256, 0, stream>>>(x, xh, xlo_, N * IN_DIM / 4);

    // CSR build (by destination)
    hipMemsetAsync(cnt, 0, (size_t)N * 4, stream);
    hist_kernel<<<(E + 255) / 256, 256, 0, stream>>>(edst, cnt, E);
    scan_partial_kernel<<<nb, 256, 0, stream>>>(cnt, partials, N);
    scan_top_kernel<<<1, 1024, 0, stream>>>(partials, nb);
    scan_final_kernel<<<nb, 256, 0, stream>>>(cnt, partials, startA, cursor, N);
    scatter_kernel<<<(E + 255) / 256, 256, 0, stream>>>(esrc, edst, cursor, srcs, srcsOff, E);

    dim3 ggrid((N + 127) / 128, 6);
    // layer 0
    gemm_pair_async<<<ggrid, 256, 0, stream>>>(xh, xlo_, Bl0h, Bl0l, bl0, xlf, Br0h, Br0l, br0, xrf, N, IN_DIM);
    agg_kernel<<<N, 64, 0, stream>>>(xlf, xrf, attH, bias0, startA, srcsOff,
                                     h0h, h0l, nullptr, nullptr, nullptr, nullptr,
                                     nullptr, nullptr, N);
    // layer 1
    gemm_pair_async<<<ggrid, 256, 0, stream>>>(h0h, h0l, Bl1h, Bl1l, bl1, xlf, Br1h, Br1l, br1, xrf, N, HID);
    agg_kernel<<<N, 64, 0, stream>>>(xlf, xrf, attH + 384, bias1, startA, srcsOff,
                                     nullptr, nullptr, Wlo, blo, Wro, bro,
                                     xloB, xroB, N);
    // output aggregation (8 lanes/node)
    out_agg_kernel<<<((size_t)N * 8 + 255) / 256, 256, 0, stream>>>(xloB, xroB, atto, biaso, startA, srcs, (float*)d_out, N);
}